// Round 8
// baseline (261.730 us; speedup 1.0000x reference)
//
#include <hip/hip_runtime.h>
#include <hip/hip_bf16.h>
#include <cstdint>
#include <cstddef>

// ---------------------------------------------------------------------------
// LRU layer (fp32 I/O): h = scan( (x W_in^T + b_in)*gamma, lambda, mask )
//                       out = LN( Re(h W_out^T + b_out) + x )
// B=8 L=2048 D=512 H=1024.
// Model (r2-r7): gemm cycles ~ staged bytes at ~15 B/cy/CU with ~3 resident
// blocks; staging rate = in-flight/latency -> raise residency to 4 blocks/CU
// via 128x128 BK=64 tiles at __launch_bounds__(256,4) (LDS 32KB, ~124 reg).
// 5-kernel pipeline: prep_all -> gemm1 -> scan_fin -> scan_full(+carry) ->
// gemm2 -> ln  (carry fused into scan_full; conv fused into prep_all).
// ---------------------------------------------------------------------------

typedef unsigned short u16;
typedef __attribute__((ext_vector_type(8))) short bf16x8;   // 8 bf16 = 4 VGPRs
typedef __attribute__((ext_vector_type(4))) float f32x4;

#define B_    8
#define L_    2048
#define D_    512
#define H_    1024
#define M_    (B_ * L_)      // 16384 rows
#define SEG_  64             // scan segments (512 blocks)
#define T_    (L_ / SEG_)    // 32 steps/segment

__device__ __forceinline__ float b2f(u16 u) {
  union { unsigned int i; float f; } v; v.i = ((unsigned int)u) << 16; return v.f;
}
__device__ __forceinline__ u16 f2b(float f) {
  union { float f; unsigned int i; } v; v.f = f;
  unsigned int x = v.i;
  return (u16)((x + 0x7fffu + ((x >> 16) & 1u)) >> 16);   // RNE
}

// async global->LDS, 16B per lane. LDS dst must be uniform-base + lane*16.
__device__ __forceinline__ void gl2lds16(const void* g, void* l) {
  __builtin_amdgcn_global_load_lds(
      (const __attribute__((address_space(1))) void*)g,
      (__attribute__((address_space(3))) void*)l, 16, 0, 0);
}

// XOR swizzle of the 8 16B-chunks in a 64-wide K row (BK=64).
__device__ __forceinline__ int ksw8(int row, int c) {
  return (c ^ (row & 7)) & 7;
}

// ---------------------------------------------------------------------------
// prep_all: x fp32->bf16 (4 float4-groups/thread) + weight prep:
//   winb[n][k] = bf16(W_in[n][k] * gamma[n&1023]),  rows [re(1024) | im(1024)]
//   wcat[d][c]=W_out_re[d][c], wcat[d][1024+c]=-W_out_im[d][c]
//   bb[n] = b_in[n] * gamma[n&1023]   (fp32, 2048)
// ---------------------------------------------------------------------------
__global__ __launch_bounds__(256) void prep_all(
    const float* __restrict__ x, u16* __restrict__ xb,
    const float* __restrict__ wire, const float* __restrict__ wiim,
    const float* __restrict__ wore, const float* __restrict__ woim,
    const float* __restrict__ bire, const float* __restrict__ biim,
    const float* __restrict__ params,
    u16* __restrict__ winb, u16* __restrict__ wcat, float* __restrict__ bb)
{
  int i = blockIdx.x * 256 + threadIdx.x;        // 0 .. 524287
  // x conversion: 2097152 float4 groups, 4 per thread
#pragma unroll
  for (int j = 0; j < 4; ++j) {
    int gi = i + j * 524288;
    float4 v = ((const float4*)x)[gi];
    ushort4 o;
    o.x = f2b(v.x); o.y = f2b(v.y); o.z = f2b(v.z); o.w = f2b(v.w);
    ((ushort4*)xb)[gi] = o;
  }
  float g = expf(params[2 * H_ + (i >> 9)]);     // gamma for W_in row i>>9
  winb[i]           = f2b(wire[i] * g);
  winb[H_ * D_ + i] = f2b(wiim[i] * g);
  int d = i >> 10, c = i & 1023;
  wcat[(size_t)d * 2048 + c]        = f2b(wore[i]);
  wcat[(size_t)d * 2048 + 1024 + c] = f2b(-woim[i]);
  if (i < 2048) {
    float gb = expf(params[2 * H_ + (i & (H_ - 1))]);
    bb[i] = ((i < 1024) ? bire[i] : biim[i - 1024]) * gb;
  }
}

// ---------------------------------------------------------------------------
// gemm_bt: C(M x N) = A(M x K) * B(N x K)^T.  128x128 tile, 4 waves 2x2
// (64x64 each, 4x4 of 16x16x32 MFMA), BK=64, LDS-DMA staging.
// __launch_bounds__(256,4): 4 blocks/CU (LDS 32KB, ~60 arch + 64 acc regs).
// Operand-swapped MFMA: D row (q*4+i) = n, col (r) = m -> 4-consecutive-n
// packed stores.  Grid: blockIdx.x = m-block (fast) -> A-sharers on one XCD.
// MODE 0: out bf16, val = acc + p0[n];  MODE 1: out fp32, val = acc + p0[n].
// ---------------------------------------------------------------------------
template <int MODE>
__global__ __launch_bounds__(256, 4) void gemm_bt(
    const u16* __restrict__ A, const u16* __restrict__ Bp, int K,
    void* __restrict__ outp, int ldc, const float* __restrict__ p0)
{
  __shared__ __align__(16) u16 sA[128 * 64];   // 16 KB
  __shared__ __align__(16) u16 sB[128 * 64];   // 16 KB

  const int tid  = threadIdx.x;
  const int lane = tid & 63;
  const int wave = tid >> 6;
  const int wm = wave >> 1, wn = wave & 1;
  const int m0 = blockIdx.x * 128;
  const int n0 = blockIdx.y * 128;

  f32x4 acc[4][4];
#pragma unroll
  for (int i = 0; i < 4; ++i)
#pragma unroll
    for (int j = 0; j < 4; ++j) { f32x4 z = {0.f, 0.f, 0.f, 0.f}; acc[i][j] = z; }

  const int q = lane >> 4;
  const int r = lane & 15;

  for (int k0 = 0; k0 < K; k0 += 64) {
#pragma unroll
    for (int it = 0; it < 4; ++it) {
      int ci  = it * 256 + tid;
      int row = ci >> 3;
      int kc  = ksw8(row, ci & 7);
      gl2lds16(A  + (size_t)(m0 + row) * K + k0 + kc * 8, &sA[ci * 8]);
      gl2lds16(Bp + (size_t)(n0 + row) * K + k0 + kc * 8, &sB[ci * 8]);
    }
    __syncthreads();

#pragma unroll
    for (int kk = 0; kk < 2; ++kk) {
      const int cs = kk * 4 + q;
      bf16x8 af[4], bfv[4];
#pragma unroll
      for (int mt = 0; mt < 4; ++mt) {
        int arow = wm * 64 + mt * 16 + r;
        int slot = arow * 8 + ksw8(arow, cs);
        af[mt] = *(const bf16x8*)&sA[slot * 8];
      }
#pragma unroll
      for (int nt = 0; nt < 4; ++nt) {
        int brow = wn * 64 + nt * 16 + r;
        int slot = brow * 8 + ksw8(brow, cs);
        bfv[nt] = *(const bf16x8*)&sB[slot * 8];
      }
#pragma unroll
      for (int mt = 0; mt < 4; ++mt)
#pragma unroll
        for (int nt = 0; nt < 4; ++nt)
          acc[mt][nt] = __builtin_amdgcn_mfma_f32_16x16x32_bf16(
              bfv[nt], af[mt], acc[mt][nt], 0, 0, 0);
    }
    __syncthreads();
  }

#pragma unroll
  for (int nt = 0; nt < 4; ++nt) {
    const int nb4 = n0 + wn * 64 + nt * 16 + q * 4;
    const float4 b4 = *(const float4*)&p0[nb4];
#pragma unroll
    for (int mt = 0; mt < 4; ++mt) {
      const int mg = m0 + wm * 64 + mt * 16 + r;
      if (MODE == 0) {
        ushort4 o;
        o.x = f2b(acc[mt][nt][0] + b4.x);
        o.y = f2b(acc[mt][nt][1] + b4.y);
        o.z = f2b(acc[mt][nt][2] + b4.z);
        o.w = f2b(acc[mt][nt][3] + b4.w);
        *(ushort4*)&((u16*)outp)[(size_t)mg * ldc + nb4] = o;
      } else {
        float4 o;
        o.x = acc[mt][nt][0] + b4.x;
        o.y = acc[mt][nt][1] + b4.y;
        o.z = acc[mt][nt][2] + b4.z;
        o.w = acc[mt][nt][3] + b4.w;
        *(float4*)&((float*)outp)[(size_t)mg * ldc + nb4] = o;
      }
    }
  }
}

// ---------------------------------------------------------------------------
// Scan pass 1 (read-only): segment-final state (zero init) + mask product.
// 8-row chunks, double-buffered.  h_t = x_t + lambda*m[t-1]*h_{t-1}.
// prodm includes the incoming-edge factor mask[t0-1] (0 for t0==0).
// ---------------------------------------------------------------------------
__global__ __launch_bounds__(256) void scan_fin(
    const u16* __restrict__ h, const float* __restrict__ mask,
    const float* __restrict__ params, float2* __restrict__ segfin,
    float* __restrict__ prodm)
{
  const int s = blockIdx.x, b = blockIdx.y;
  const int c4 = threadIdx.x * 4;
  float lr[4], li[4];
#pragma unroll
  for (int j = 0; j < 4; ++j) {
    int c = c4 + j;
    float nu = expf(params[c]);
    float th = expf(params[H_ + c]);
    float mg = expf(-nu);
    lr[j] = mg * cosf(th);
    li[j] = mg * sinf(th);
  }
  const int t0 = s * T_;
  const u16* p = h + (size_t)(b * L_ + t0) * (2 * H_) + c4;
  const float* mp = mask + b * L_ + t0;
  float fac0;
  if (t0 == 0) fac0 = 0.f; else fac0 = mask[b * L_ + t0 - 1];

  ushort4 bre[2][8], bim[2][8];
#pragma unroll
  for (int j = 0; j < 8; ++j) {
    bre[0][j] = *(const ushort4*)(p + (size_t)j * 2 * H_);
    bim[0][j] = *(const ushort4*)(p + (size_t)j * 2 * H_ + H_);
  }
  float sr[4] = {0, 0, 0, 0}, si[4] = {0, 0, 0, 0};
  float pm = 1.f;
#pragma unroll
  for (int ch = 0; ch < T_ / 8; ++ch) {
    const int cur = ch & 1, nxt = cur ^ 1;
    if (ch < T_ / 8 - 1) {
      const u16* pn = p + (size_t)(ch + 1) * 8 * 2 * H_;
#pragma unroll
      for (int j = 0; j < 8; ++j) {
        bre[nxt][j] = *(const ushort4*)(pn + (size_t)j * 2 * H_);
        bim[nxt][j] = *(const ushort4*)(pn + (size_t)j * 2 * H_ + H_);
      }
    }
#pragma unroll
    for (int j = 0; j < 8; ++j) {
      int i = ch * 8 + j;
      float fac = (i == 0) ? fac0 : mp[i - 1];
      pm *= fac;
      u16 rr[4], ii[4];
      *(ushort4*)rr = bre[cur][j]; *(ushort4*)ii = bim[cur][j];
#pragma unroll
      for (int k = 0; k < 4; ++k) {
        float ar = fac * sr[k], ai = fac * si[k];
        sr[k] = b2f(rr[k]) + lr[k] * ar - li[k] * ai;
        si[k] = b2f(ii[k]) + lr[k] * ai + li[k] * ar;
      }
    }
  }
#pragma unroll
  for (int j = 0; j < 4; ++j)
    segfin[(size_t)(b * SEG_ + s) * H_ + c4 + j] = make_float2(sr[j], si[j]);
  if (threadIdx.x == 0) prodm[b * SEG_ + s] = pm;
}

// ---------------------------------------------------------------------------
// Scan pass 2 (fused carry + full rewrite): each block first recomputes the
// carry entering its segment by scanning segfin/prodm for s' < s (L2-hit
// loads, <=63 iters of complex FMA), then does the full in-place scan.
// carry_{s'+1} = fin_{s'} + prodm_{s'} * lambda^T * carry_{s'}.
// ---------------------------------------------------------------------------
__global__ __launch_bounds__(256) void scan_full(
    u16* __restrict__ h, const float* __restrict__ mask,
    const float* __restrict__ params, const float2* __restrict__ segfin,
    const float* __restrict__ prodm)
{
  const int s = blockIdx.x, b = blockIdx.y;
  const int c4 = threadIdx.x * 4;
  float lr[4], li[4], sr[4], si[4];
#pragma unroll
  for (int j = 0; j < 4; ++j) {
    int c = c4 + j;
    float nu = expf(params[c]);
    float th = expf(params[H_ + c]);
    float mg = expf(-nu);
    lr[j] = mg * cosf(th);
    li[j] = mg * sinf(th);
    sr[j] = 0.f; si[j] = 0.f;
  }
  // lambda^T via 5 squarings (T=32)
  float ltr[4], lti[4];
#pragma unroll
  for (int j = 0; j < 4; ++j) { ltr[j] = lr[j]; lti[j] = li[j]; }
#pragma unroll
  for (int sq = 0; sq < 5; ++sq)
#pragma unroll
    for (int j = 0; j < 4; ++j) {
      float nr = ltr[j] * ltr[j] - lti[j] * lti[j];
      float ni = 2.f * ltr[j] * lti[j];
      ltr[j] = nr; lti[j] = ni;
    }
  // carry lookback over preceding segments
  for (int sp = 0; sp < s; ++sp) {
    const float2* fp = &segfin[(size_t)(b * SEG_ + sp) * H_ + c4];
    float pmv = prodm[b * SEG_ + sp];
#pragma unroll
    for (int j = 0; j < 4; ++j) {
      float2 fin = fp[j];
      float nr = fin.x + pmv * (ltr[j] * sr[j] - lti[j] * si[j]);
      float ni = fin.y + pmv * (ltr[j] * si[j] + lti[j] * sr[j]);
      sr[j] = nr; si[j] = ni;
    }
  }

  const int t0 = s * T_;
  u16* p = h + (size_t)(b * L_ + t0) * (2 * H_) + c4;
  const float* mp = mask + b * L_ + t0;
  float fac0;
  if (t0 == 0) fac0 = 0.f; else fac0 = mask[b * L_ + t0 - 1];

  ushort4 bre[2][8], bim[2][8];
#pragma unroll
  for (int j = 0; j < 8; ++j) {
    bre[0][j] = *(const ushort4*)(p + (size_t)j * 2 * H_);
    bim[0][j] = *(const ushort4*)(p + (size_t)j * 2 * H_ + H_);
  }
#pragma unroll
  for (int ch = 0; ch < T_ / 8; ++ch) {
    const int cur = ch & 1, nxt = cur ^ 1;
    if (ch < T_ / 8 - 1) {
      const u16* pn = p + (size_t)(ch + 1) * 8 * 2 * H_;
#pragma unroll
      for (int j = 0; j < 8; ++j) {
        bre[nxt][j] = *(const ushort4*)(pn + (size_t)j * 2 * H_);
        bim[nxt][j] = *(const ushort4*)(pn + (size_t)j * 2 * H_ + H_);
      }
    }
#pragma unroll
    for (int j = 0; j < 8; ++j) {
      int i = ch * 8 + j;
      float fac = (i == 0) ? fac0 : mp[i - 1];
      u16 rr[4], ii[4], orr[4], oii[4];
      *(ushort4*)rr = bre[cur][j]; *(ushort4*)ii = bim[cur][j];
#pragma unroll
      for (int k = 0; k < 4; ++k) {
        float ar = fac * sr[k], ai = fac * si[k];
        float nr2 = b2f(rr[k]) + lr[k] * ar - li[k] * ai;
        float ni2 = b2f(ii[k]) + lr[k] * ai + li[k] * ar;
        sr[k] = nr2; si[k] = ni2;
        orr[k] = f2b(nr2); oii[k] = f2b(ni2);
      }
      *(ushort4*)(p + (size_t)i * 2 * H_)      = *(ushort4*)orr;
      *(ushort4*)(p + (size_t)i * 2 * H_ + H_) = *(ushort4*)oii;
    }
  }
}

// ---------------------------------------------------------------------------
// LayerNorm: z = y + x; out = (z-mean)/sqrt(var+eps)*w + b.
// ---------------------------------------------------------------------------
__global__ __launch_bounds__(256) void ln_kernel(
    const float* __restrict__ y, const float* __restrict__ xg,
    const float* __restrict__ lnw, const float* __restrict__ lnb,
    float* __restrict__ out)
{
  const int wave = threadIdx.x >> 6, lane = threadIdx.x & 63;
  const size_t row = (size_t)blockIdx.x * 4 + wave;
  const float* yr = y + row * 512;
  const float* xr = xg + row * 512;
  float z[8];
  { float4 t = *(const float4*)&yr[lane * 4];        z[0]=t.x; z[1]=t.y; z[2]=t.z; z[3]=t.w; }
  { float4 t = *(const float4*)&yr[256 + lane * 4];  z[4]=t.x; z[5]=t.y; z[6]=t.z; z[7]=t.w; }
  { float4 t = *(const float4*)&xr[lane * 4];        z[0]+=t.x; z[1]+=t.y; z[2]+=t.z; z[3]+=t.w; }
  { float4 t = *(const float4*)&xr[256 + lane * 4];  z[4]+=t.x; z[5]+=t.y; z[6]+=t.z; z[7]+=t.w; }
  float s = 0.f, ss = 0.f;
#pragma unroll
  for (int j = 0; j < 8; ++j) { s += z[j]; ss += z[j] * z[j]; }
#pragma unroll
  for (int o = 32; o > 0; o >>= 1) { s += __shfl_xor(s, o); ss += __shfl_xor(ss, o); }
  const float mean = s * (1.f / 512.f);
  const float var  = ss * (1.f / 512.f) - mean * mean;
  const float inv  = rsqrtf(var + 1e-5f);
  float ov[8];
#pragma unroll
  for (int j = 0; j < 8; ++j) {
    int col = (j < 4) ? (lane * 4 + j) : (256 + lane * 4 + (j - 4));
    ov[j] = (z[j] - mean) * inv * lnw[col] + lnb[col];
  }
  { float4 t; t.x=ov[0]; t.y=ov[1]; t.z=ov[2]; t.w=ov[3];
    *(float4*)&out[row * 512 + lane * 4] = t; }
  { float4 t; t.x=ov[4]; t.y=ov[5]; t.z=ov[6]; t.w=ov[7];
    *(float4*)&out[row * 512 + 256 + lane * 4] = t; }
}

// ---------------------------------------------------------------------------
extern "C" void kernel_launch(void* const* d_in, const int* in_sizes, int n_in,
                              void* d_out, int out_size, void* d_ws, size_t ws_size,
                              hipStream_t stream) {
  (void)in_sizes; (void)n_in; (void)out_size; (void)ws_size;
  const float* x      = (const float*)d_in[0];
  const float* mask   = (const float*)d_in[1];
  const float* params = (const float*)d_in[2];   // [3][1024]: nu_log, theta_log, gamma_log
  const float* Wire   = (const float*)d_in[3];
  const float* Wiim   = (const float*)d_in[4];
  const float* bire   = (const float*)d_in[5];
  const float* biim   = (const float*)d_in[6];
  const float* Wore   = (const float*)d_in[7];
  const float* Woim   = (const float*)d_in[8];
  const float* bore   = (const float*)d_in[9];
  // d_in[10] = b_out_im: only affects Im(y), discarded by .real
  const float* lnw    = (const float*)d_in[11];
  const float* lnb    = (const float*)d_in[12];

  // Workspace (~105 MB). Region [0, 33.5M) time-shared:
  //   xb (gemm1 in) -> segfin[0,4M)+prodm[8M) -> y (gemm2/ln)
  char* ws = (char*)d_ws;
  u16*    xb      = (u16*)   (ws);                         // 16384*512*2 = 16.7M
  float2* segfin  = (float2*)(ws);                         // 8*64*1024*8 = 4M
  float*  prodm   = (float*) (ws + (size_t)8388608);       // 2 KB
  float*  y       = (float*) (ws);                         // 16384*512*4 = 33.5M
  u16*    h       = (u16*)   (ws + (size_t)33554432);      // 16384*2048*2 = 67M
  u16*    winb    = (u16*)   (ws + (size_t)100663296);     // 2048*512*2 = 2M
  u16*    wcat    = (u16*)   (ws + (size_t)102760448);     // 512*2048*2 = 2M
  float*  bb      = (float*) (ws + (size_t)104857600);     // 2048*4 = 8 KB

  prep_all<<<2048, 256, 0, stream>>>(x, xb, Wire, Wiim, Wore, Woim,
                                     bire, biim, params, winb, wcat, bb);

  // h[re|im] = x @ (gamma*[W_in_re;W_in_im])^T + bb  (M=16384,N=2048,K=512)
  gemm_bt<0><<<dim3(128, 16), 256, 0, stream>>>(
      xb, winb, 512, (void*)h, 2048, bb);

  scan_fin<<<dim3(SEG_, B_), 256, 0, stream>>>(h, mask, params, segfin, prodm);
  scan_full<<<dim3(SEG_, B_), 256, 0, stream>>>(h, mask, params, segfin, prodm);

  // y = h_cat @ Wcat^T + b_out_re   (M=16384,N=512,K=2048), fp32 out
  gemm_bt<1><<<dim3(128, 4), 256, 0, stream>>>(
      h, wcat, 2048, (void*)y, 512, bore);

  ln_kernel<<<4096, 256, 0, stream>>>(y, x, lnw, lnb, (float*)d_out);
}

// Round 10
// 240.011 us; speedup vs baseline: 1.0905x; 1.0905x over previous
//
#include <hip/hip_runtime.h>
#include <hip/hip_bf16.h>
#include <cstdint>
#include <cstddef>

// ---------------------------------------------------------------------------
// LRU layer (fp32 I/O): h = scan( (x W_in^T + b_in)*gamma, lambda, mask )
//                       out = LN( Re(h W_out^T + b_out) + x )
// B=8 L=2048 D=512 H=1024.
// Channel layout COMPLEX-INTERLEAVED (col 2c=re_c, 2c+1=im_c) for h/winb/
// wcat/bb.  gemm_scan emits the pre-scan GEMM output AND segfin/prodm (from
// its in-LDS tile) -> scan_fin pass deleted.  scan_full then runs the FULL
// recurrence (fp32 state seeded by carries) so every h element is rounded
// exactly once (round-9's add-correction double-rounding hit 0.146 absmax
// on resonant |lambda|~0.99 channels where |h|~16, ULP=0.125).
// Pipeline: prep_all -> gemm_scan -> scan_carry -> scan_full -> gemm2 -> ln.
// ---------------------------------------------------------------------------

typedef unsigned short u16;
typedef __attribute__((ext_vector_type(8))) short bf16x8;   // 8 bf16 = 4 VGPRs
typedef __attribute__((ext_vector_type(4))) float f32x4;

#define B_    8
#define L_    2048
#define D_    512
#define H_    1024
#define M_    (B_ * L_)      // 16384 rows
#define SEG_  64             // scan segments per batch
#define T_    (L_ / SEG_)    // 32 steps/segment

__device__ __forceinline__ float b2f(u16 u) {
  union { unsigned int i; float f; } v; v.i = ((unsigned int)u) << 16; return v.f;
}
__device__ __forceinline__ u16 f2b(float f) {
  union { float f; unsigned int i; } v; v.f = f;
  unsigned int x = v.i;
  return (u16)((x + 0x7fffu + ((x >> 16) & 1u)) >> 16);   // RNE
}

// async global->LDS, 16B per lane. LDS dst must be uniform-base + lane*16.
__device__ __forceinline__ void gl2lds16(const void* g, void* l) {
  __builtin_amdgcn_global_load_lds(
      (const __attribute__((address_space(1))) void*)g,
      (__attribute__((address_space(3))) void*)l, 16, 0, 0);
}

// XOR swizzle of the 8 16B-chunks in a 64-wide K row (BK=64).
__device__ __forceinline__ int ksw8(int row, int c) {
  return (c ^ (row & 7)) & 7;
}

// ---------------------------------------------------------------------------
// prep_all: x fp32->bf16 + interleaved weight prep:
//   winb[2c][k]   = bf16(W_in_re[c][k] * gamma_c)
//   winb[2c+1][k] = bf16(W_in_im[c][k] * gamma_c)
//   wcat[d][2c]   = bf16(W_out_re[d][c]);  wcat[d][2c+1] = bf16(-W_out_im[d][c])
//   bb[2c] = b_in_re[c]*gamma_c;  bb[2c+1] = b_in_im[c]*gamma_c
// ---------------------------------------------------------------------------
__global__ __launch_bounds__(256) void prep_all(
    const float* __restrict__ x, u16* __restrict__ xb,
    const float* __restrict__ wire, const float* __restrict__ wiim,
    const float* __restrict__ wore, const float* __restrict__ woim,
    const float* __restrict__ bire, const float* __restrict__ biim,
    const float* __restrict__ params,
    u16* __restrict__ winb, u16* __restrict__ wcat, float* __restrict__ bb)
{
  int i = blockIdx.x * 256 + threadIdx.x;        // 0 .. 524287
#pragma unroll
  for (int j = 0; j < 4; ++j) {                  // x: 2097152 float4 groups
    int gi = i + j * 524288;
    float4 v = ((const float4*)x)[gi];
    ushort4 o;
    o.x = f2b(v.x); o.y = f2b(v.y); o.z = f2b(v.z); o.w = f2b(v.w);
    ((ushort4*)xb)[gi] = o;
  }
  {
    int cp = i >> 9, k = i & 511;                // W_in: (pair, k)
    float g = expf(params[2 * H_ + cp]);
    winb[(size_t)(2 * cp) * 512 + k]     = f2b(wire[i] * g);
    winb[(size_t)(2 * cp + 1) * 512 + k] = f2b(wiim[i] * g);
  }
  {
    int d = i >> 10, c = i & 1023;               // W_out: (d, c)
    wcat[(size_t)d * 2048 + 2 * c]     = f2b(wore[i]);
    wcat[(size_t)d * 2048 + 2 * c + 1] = f2b(-woim[i]);
  }
  if (i < 1024) {
    float gb = expf(params[2 * H_ + i]);
    bb[2 * i]     = bire[i] * gb;
    bb[2 * i + 1] = biim[i] * gb;
  }
}

// ---------------------------------------------------------------------------
// gemm_scan: xh = x @ winb^T + bb (pre-scan) AND segfin/prodm of the
// segment-local scan over the in-LDS tile (bf16 values, identical bytes to
// what a separate scan_fin pass would re-read from global).
// 128x128 tile, BK=64, LDS-DMA staging, operand-swapped MFMA
// (D row=channel, col=time).  Epilogue: acc+bias -> bf16 -> sH (swizzled);
// coalesced global store; per-wave (wave=segment, lane=pair) fp32 local
// scan for segfin/prodm only.
// ---------------------------------------------------------------------------
__global__ __launch_bounds__(256, 4) void gemm_scan(
    const u16* __restrict__ A, const u16* __restrict__ Bp,
    const float* __restrict__ mask, const float* __restrict__ params,
    u16* __restrict__ h, const float* __restrict__ bb,
    float2* __restrict__ segfin, float* __restrict__ prodm)
{
  __shared__ __align__(16) u16 sAB[16384];   // 32 KB: sA=[0,8192) sB=[8192,..)
  __shared__ float mf[128];
  const int K = 512;

  const int tid  = threadIdx.x;
  const int lane = tid & 63;
  const int wave = tid >> 6;
  const int wm = wave >> 1, wn = wave & 1;
  const int m0 = blockIdx.x * 128;           // m fast axis (XCD A-share)
  const int n0 = blockIdx.y * 128;
  const int b  = m0 >> 11;
  const int local0 = m0 & (L_ - 1);          // row offset within batch

  f32x4 acc[4][4];
#pragma unroll
  for (int i = 0; i < 4; ++i)
#pragma unroll
    for (int j = 0; j < 4; ++j) { f32x4 z = {0.f, 0.f, 0.f, 0.f}; acc[i][j] = z; }

  const int q = lane >> 4;
  const int r = lane & 15;

  for (int k0 = 0; k0 < K; k0 += 64) {
#pragma unroll
    for (int it = 0; it < 4; ++it) {
      int ci  = it * 256 + tid;
      int row = ci >> 3;
      int kc  = ksw8(row, ci & 7);
      gl2lds16(A  + (size_t)(m0 + row) * K + k0 + kc * 8, &sAB[ci * 8]);
      gl2lds16(Bp + (size_t)(n0 + row) * K + k0 + kc * 8, &sAB[8192 + ci * 8]);
    }
    __syncthreads();
#pragma unroll
    for (int kk = 0; kk < 2; ++kk) {
      const int cs = kk * 4 + q;
      bf16x8 af[4], bfv[4];
#pragma unroll
      for (int mt = 0; mt < 4; ++mt) {
        int arow = wm * 64 + mt * 16 + r;
        af[mt] = *(const bf16x8*)&sAB[(arow * 8 + ksw8(arow, cs)) * 8];
      }
#pragma unroll
      for (int nt = 0; nt < 4; ++nt) {
        int brow = wn * 64 + nt * 16 + r;
        bfv[nt] = *(const bf16x8*)&sAB[8192 + (brow * 8 + ksw8(brow, cs)) * 8];
      }
#pragma unroll
      for (int mt = 0; mt < 4; ++mt)
#pragma unroll
        for (int nt = 0; nt < 4; ++nt)
          acc[mt][nt] = __builtin_amdgcn_mfma_f32_16x16x32_bf16(
              bfv[nt], af[mt], acc[mt][nt], 0, 0, 0);
    }
    __syncthreads();
  }

  // ---- epilogue 1: bf16(acc+bias) -> sH[time 0..127][chan 0..127] ----
  u16* sH = sAB;                               // 128*128 u16 = 32 KB
  if (tid < 128)                               // stage mask factors
    mf[tid] = (local0 + tid == 0) ? 0.f
                                  : mask[b * L_ + local0 + tid - 1];
#pragma unroll
  for (int mt = 0; mt < 4; ++mt) {
    const int trow = wm * 64 + mt * 16 + r;    // time
    const int sw = (trow & 7) << 4;
#pragma unroll
    for (int nt = 0; nt < 4; ++nt) {
      const int nc = wn * 64 + nt * 16 + q * 4;  // channel (4 consecutive)
      const float4 b4 = *(const float4*)&bb[n0 + nc];
      ushort4 o;
      o.x = f2b(acc[mt][nt][0] + b4.x);
      o.y = f2b(acc[mt][nt][1] + b4.y);
      o.z = f2b(acc[mt][nt][2] + b4.z);
      o.w = f2b(acc[mt][nt][3] + b4.w);
      *(ushort4*)&sH[trow * 128 + (nc ^ sw)] = o;
    }
  }
  __syncthreads();

  // ---- epilogue 2: coalesced pre-scan store (issues early) ----
#pragma unroll
  for (int it = 0; it < 8; ++it) {
    int flat = it * 256 + tid;                 // 0..2047 (16B chunks)
    int row  = flat >> 4;
    int c16  = (flat & 15) * 8;
    bf16x8 v = *(const bf16x8*)&sH[row * 128 + (c16 ^ ((row & 7) << 4))];
    *(bf16x8*)&h[(size_t)(m0 + row) * 2048 + n0 + c16] = v;
  }

  // ---- epilogue 3: per-wave segment scan -> segfin/prodm only ----
  {
    const int sIdx = wave;                     // 4 segments per block
    const int cpG  = (n0 >> 1) + lane;         // global complex pair
    float nu = expf(params[cpG]);
    float th = expf(params[H_ + cpG]);
    float mg = expf(-nu);
    float lr = mg * cosf(th), li = mg * sinf(th);
    float sr = 0.f, si = 0.f, pm = 1.f;
    const int rbase = sIdx * 32;
#pragma unroll
    for (int t = 0; t < 32; ++t) {
      int row = rbase + t;
      int pos = row * 128 + ((lane * 2) ^ ((row & 7) << 4));
      ushort2 v = *(const ushort2*)&sH[pos];
      float fac = mf[row];
      pm *= fac;
      float nr = b2f(v.x) + fac * (lr * sr - li * si);
      float ni = b2f(v.y) + fac * (lr * si + li * sr);
      sr = nr; si = ni;
    }
    const int sG = (local0 >> 5) + sIdx;       // global segment in batch
    segfin[(size_t)(b * SEG_ + sG) * H_ + cpG] = make_float2(sr, si);
    if (lane == 0 && n0 == 0) prodm[b * SEG_ + sG] = pm;
  }
}

// ---------------------------------------------------------------------------
// scan_carry: carries[s] = state entering segment s.
// carry_{s+1} = fin_s + prodm_s * lambda^T * carry_s; lambda^T via 5 sq.
// ---------------------------------------------------------------------------
__global__ __launch_bounds__(256) void scan_carry(
    const float2* __restrict__ segfin, const float* __restrict__ prodm,
    const float* __restrict__ params, float2* __restrict__ carries)
{
  int idx = blockIdx.x * 256 + threadIdx.x;   // 0..8191
  int b = idx >> 10, cp = idx & 1023;
  float nu = expf(params[cp]);
  float th = expf(params[H_ + cp]);
  float mg = expf(-nu);
  float ltr = mg * cosf(th), lti = mg * sinf(th);
#pragma unroll
  for (int sq = 0; sq < 5; ++sq) {            // lambda^(2^5), T=32
    float nr = ltr * ltr - lti * lti;
    float ni = 2.f * ltr * lti;
    ltr = nr; lti = ni;
  }
  float cr = 0.f, ci = 0.f;
  float2 fin = segfin[(size_t)(b * SEG_) * H_ + cp];
  float pmv = prodm[b * SEG_];
  for (int s = 0; s < SEG_; ++s) {
    size_t o = (size_t)(b * SEG_ + s) * H_ + cp;
    carries[o] = make_float2(cr, ci);
    float2 finn; float pmn;
    if (s + 1 < SEG_) { finn = segfin[o + H_]; pmn = prodm[b * SEG_ + s + 1]; }
    float nr = fin.x + pmv * (ltr * cr - lti * ci);
    float ni = fin.y + pmv * (ltr * ci + lti * cr);
    cr = nr; ci = ni;
    fin = finn; pmv = pmn;
  }
}

// ---------------------------------------------------------------------------
// scan_full: FULL recurrence per segment, fp32 state seeded from carries;
// h rewritten in place with exactly one bf16 rounding per element.
// Interleaved layout: thread = 4 complex pairs = one bf16x8 per row.
// 8-row chunks, double-buffered loads.
// ---------------------------------------------------------------------------
__global__ __launch_bounds__(256) void scan_full(
    u16* __restrict__ h, const float* __restrict__ mask,
    const float* __restrict__ params, const float2* __restrict__ carries)
{
  const int s = blockIdx.x, b = blockIdx.y;
  const int pa = threadIdx.x * 4;              // first of 4 pairs
  float lr[4], li[4], sr[4], si[4];
#pragma unroll
  for (int j = 0; j < 4; ++j) {
    int cp = pa + j;
    float nu = expf(params[cp]);
    float th = expf(params[H_ + cp]);
    float mg = expf(-nu);
    lr[j] = mg * cosf(th);
    li[j] = mg * sinf(th);
    float2 cv = carries[(size_t)(b * SEG_ + s) * H_ + cp];
    sr[j] = cv.x; si[j] = cv.y;
  }
  const int t0 = s * T_;
  u16* p = h + (size_t)(b * L_ + t0) * 2048 + pa * 2;
  const float* mp = mask + b * L_ + t0;
  float fac0;                                  // block-uniform, no OOB
  if (t0 == 0) fac0 = 0.f; else fac0 = mask[b * L_ + t0 - 1];

  bf16x8 buf[2][8];
#pragma unroll
  for (int j = 0; j < 8; ++j)
    buf[0][j] = *(const bf16x8*)(p + (size_t)j * 2048);
#pragma unroll
  for (int ch = 0; ch < T_ / 8; ++ch) {
    const int cur = ch & 1, nxt = cur ^ 1;
    if (ch < T_ / 8 - 1) {
      u16* pn = p + (size_t)(ch + 1) * 8 * 2048;
#pragma unroll
      for (int j = 0; j < 8; ++j)
        buf[nxt][j] = *(const bf16x8*)(pn + (size_t)j * 2048);
    }
#pragma unroll
    for (int j = 0; j < 8; ++j) {
      int i = ch * 8 + j;
      float fac = (i == 0) ? fac0 : mp[i - 1];
      u16 vv[8], ov[8];
      *(bf16x8*)vv = buf[cur][j];
#pragma unroll
      for (int k = 0; k < 4; ++k) {
        float ar = fac * sr[k], ai = fac * si[k];
        float nr = b2f(vv[2 * k])     + lr[k] * ar - li[k] * ai;
        float ni = b2f(vv[2 * k + 1]) + lr[k] * ai + li[k] * ar;
        sr[k] = nr; si[k] = ni;
        ov[2 * k]     = f2b(nr);
        ov[2 * k + 1] = f2b(ni);
      }
      *(bf16x8*)(p + (size_t)i * 2048) = *(bf16x8*)ov;
    }
  }
}

// ---------------------------------------------------------------------------
// gemm2: y = h @ wcat^T + b_out_re.  128x128 tile BK=64, LDS-DMA staging,
// operand-swapped epilogue, fp32 out.
// ---------------------------------------------------------------------------
__global__ __launch_bounds__(256, 4) void gemm2(
    const u16* __restrict__ A, const u16* __restrict__ Bp, int K,
    float* __restrict__ outp, int ldc, const float* __restrict__ p0)
{
  __shared__ __align__(16) u16 sA[128 * 64];
  __shared__ __align__(16) u16 sB[128 * 64];

  const int tid  = threadIdx.x;
  const int lane = tid & 63;
  const int wave = tid >> 6;
  const int wm = wave >> 1, wn = wave & 1;
  const int m0 = blockIdx.x * 128;
  const int n0 = blockIdx.y * 128;

  f32x4 acc[4][4];
#pragma unroll
  for (int i = 0; i < 4; ++i)
#pragma unroll
    for (int j = 0; j < 4; ++j) { f32x4 z = {0.f, 0.f, 0.f, 0.f}; acc[i][j] = z; }

  const int q = lane >> 4;
  const int r = lane & 15;

  for (int k0 = 0; k0 < K; k0 += 64) {
#pragma unroll
    for (int it = 0; it < 4; ++it) {
      int ci  = it * 256 + tid;
      int row = ci >> 3;
      int kc  = ksw8(row, ci & 7);
      gl2lds16(A  + (size_t)(m0 + row) * K + k0 + kc * 8, &sA[ci * 8]);
      gl2lds16(Bp + (size_t)(n0 + row) * K + k0 + kc * 8, &sB[ci * 8]);
    }
    __syncthreads();
#pragma unroll
    for (int kk = 0; kk < 2; ++kk) {
      const int cs = kk * 4 + q;
      bf16x8 af[4], bfv[4];
#pragma unroll
      for (int mt = 0; mt < 4; ++mt) {
        int arow = wm * 64 + mt * 16 + r;
        af[mt] = *(const bf16x8*)&sA[(arow * 8 + ksw8(arow, cs)) * 8];
      }
#pragma unroll
      for (int nt = 0; nt < 4; ++nt) {
        int brow = wn * 64 + nt * 16 + r;
        bfv[nt] = *(const bf16x8*)&sB[(brow * 8 + ksw8(brow, cs)) * 8];
      }
#pragma unroll
      for (int mt = 0; mt < 4; ++mt)
#pragma unroll
        for (int nt = 0; nt < 4; ++nt)
          acc[mt][nt] = __builtin_amdgcn_mfma_f32_16x16x32_bf16(
              bfv[nt], af[mt], acc[mt][nt], 0, 0, 0);
    }
    __syncthreads();
  }

#pragma unroll
  for (int nt = 0; nt < 4; ++nt) {
    const int nb4 = n0 + wn * 64 + nt * 16 + q * 4;
    const float4 b4 = *(const float4*)&p0[nb4];
#pragma unroll
    for (int mt = 0; mt < 4; ++mt) {
      const int mg = m0 + wm * 64 + mt * 16 + r;
      float4 o;
      o.x = acc[mt][nt][0] + b4.x;
      o.y = acc[mt][nt][1] + b4.y;
      o.z = acc[mt][nt][2] + b4.z;
      o.w = acc[mt][nt][3] + b4.w;
      *(float4*)&outp[(size_t)mg * ldc + nb4] = o;
    }
  }
}

// ---------------------------------------------------------------------------
// LayerNorm: z = y + x; out = (z-mean)/sqrt(var+eps)*w + b.
// ---------------------------------------------------------------------------
__global__ __launch_bounds__(256) void ln_kernel(
    const float* __restrict__ y, const float* __restrict__ xg,
    const float* __restrict__ lnw, const float* __restrict__ lnb,
    float* __restrict__ out)
{
  const int wave = threadIdx.x >> 6, lane = threadIdx.x & 63;
  const size_t row = (size_t)blockIdx.x * 4 + wave;
  const float* yr = y + row * 512;
  const float* xr = xg + row * 512;
  float z[8];
  { float4 t = *(const float4*)&yr[lane * 4];        z[0]=t.x; z[1]=t.y; z[2]=t.z; z[3]=t.w; }
  { float4 t = *(const float4*)&yr[256 + lane * 4];  z[4]=t.x; z[5]=t.y; z[6]=t.z; z[7]=t.w; }
  { float4 t = *(const float4*)&xr[lane * 4];        z[0]+=t.x; z[1]+=t.y; z[2]+=t.z; z[3]+=t.w; }
  { float4 t = *(const float4*)&xr[256 + lane * 4];  z[4]+=t.x; z[5]+=t.y; z[6]+=t.z; z[7]+=t.w; }
  float s = 0.f, ss = 0.f;
#pragma unroll
  for (int j = 0; j < 8; ++j) { s += z[j]; ss += z[j] * z[j]; }
#pragma unroll
  for (int o = 32; o > 0; o >>= 1) { s += __shfl_xor(s, o); ss += __shfl_xor(ss, o); }
  const float mean = s * (1.f / 512.f);
  const float var  = ss * (1.f / 512.f) - mean * mean;
  const float inv  = rsqrtf(var + 1e-5f);
  float ov[8];
#pragma unroll
  for (int j = 0; j < 8; ++j) {
    int col = (j < 4) ? (lane * 4 + j) : (256 + lane * 4 + (j - 4));
    ov[j] = (z[j] - mean) * inv * lnw[col] + lnb[col];
  }
  { float4 t; t.x=ov[0]; t.y=ov[1]; t.z=ov[2]; t.w=ov[3];
    *(float4*)&out[row * 512 + lane * 4] = t; }
  { float4 t; t.x=ov[4]; t.y=ov[5]; t.z=ov[6]; t.w=ov[7];
    *(float4*)&out[row * 512 + 256 + lane * 4] = t; }
}

// ---------------------------------------------------------------------------
extern "C" void kernel_launch(void* const* d_in, const int* in_sizes, int n_in,
                              void* d_out, int out_size, void* d_ws, size_t ws_size,
                              hipStream_t stream) {
  (void)in_sizes; (void)n_in; (void)out_size; (void)ws_size;
  const float* x      = (const float*)d_in[0];
  const float* mask   = (const float*)d_in[1];
  const float* params = (const float*)d_in[2];   // [3][1024]
  const float* Wire   = (const float*)d_in[3];
  const float* Wiim   = (const float*)d_in[4];
  const float* bire   = (const float*)d_in[5];
  const float* biim   = (const float*)d_in[6];
  const float* Wore   = (const float*)d_in[7];
  const float* Woim   = (const float*)d_in[8];
  const float* bore   = (const float*)d_in[9];
  // d_in[10] = b_out_im: only affects Im(y), discarded by .real
  const float* lnw    = (const float*)d_in[11];
  const float* lnb    = (const float*)d_in[12];

  // Workspace (~105 MB).
  //   [0, 16.7M):        xb (gemm1 input); later y [0, 33.5M) (gemm2/ln)
  //   [16.7M, 25.2M):    segfin 4M | carries 4M | prodm  (dead before gemm2)
  //   [33.5M, 100.7M):   h (67 MB)
  //   [100.7M .. ]:      winb 2M | wcat 2M | bb 8K
  char* ws = (char*)d_ws;
  u16*    xb      = (u16*)   (ws);
  float*  y       = (float*) (ws);
  float2* segfin  = (float2*)(ws + (size_t)16777216);
  float2* carries = (float2*)(ws + (size_t)20971520);
  float*  prodm   = (float*) (ws + (size_t)25165824);
  u16*    h       = (u16*)   (ws + (size_t)33554432);
  u16*    winb    = (u16*)   (ws + (size_t)100663296);
  u16*    wcat    = (u16*)   (ws + (size_t)102760448);
  float*  bb      = (float*) (ws + (size_t)104857600);

  prep_all<<<2048, 256, 0, stream>>>(x, xb, Wire, Wiim, Wore, Woim,
                                     bire, biim, params, winb, wcat, bb);

  // xh = x @ winb^T + bb (pre-scan) + segfin/prodm   (M=16384,N=2048,K=512)
  gemm_scan<<<dim3(128, 16), 256, 0, stream>>>(
      xb, winb, mask, params, h, bb, segfin, prodm);

  scan_carry<<<32, 256, 0, stream>>>(segfin, prodm, params, carries);
  scan_full<<<dim3(SEG_, B_), 256, 0, stream>>>(h, mask, params, carries);

  // y = h @ wcat^T + b_out_re   (M=16384, N=512, K=2048)
  gemm2<<<dim3(128, 4), 256, 0, stream>>>(h, wcat, 2048, y, 512, bore);

  ln_kernel<<<4096, 256, 0, stream>>>(y, x, lnw, lnb, (float*)d_out);
}